// Round 3
// baseline (151.681 us; speedup 1.0000x reference)
//
#include <hip/hip_runtime.h>
#include <hip/hip_bf16.h>

// feature [B=128, E=64, D=128] fp32 -> N = 8192 rows of dim 128.
// loss = mean_r( log(den_r) - log(pos_r) ),
//   den_r = sum_c exp(10*<f_r,f_c>), pos_r = sum over c in r's 64-row block.
//
// v4: v3 (no-LDS, direct-L2 fragments) was latency-bound at 18% occupancy
// (grid 512 blocks = 2/CU = 2 waves/SIMD; MfmaUtil 13%). LDS=0 and VGPR=92
// allow ~5 waves/SIMD, so the grid was the limiter. CPG 8->2 gives 2048
// blocks = 8/CU queued (~5 resident), ~20 waves/CU, trading a little extra
// A-fragment L2 traffic (hidden) for 3.4x more latency-hiding waves.
#define N_ROWS 8192
#define DIM    128
#define TILE   128
#define CPG    2     // col tiles per block
#define EXPTEN 22026.465794806718f  // exp(10.0)
// Xb = normalize(f) * SCALE, SCALE^2 = 10*log2(e); then exp2(dot) = exp(10*<f,f>)
#define SCALE  3.7982826f

typedef __attribute__((ext_vector_type(8))) short short8;   // 8 bf16 = 4 VGPRs
typedef __attribute__((ext_vector_type(4))) float floatx4;  // MFMA C/D

#define EXP2F(x) __builtin_amdgcn_exp2f(x)

// ---- Kernel 1: L2-normalize rows, scale, cast to bf16; zero pos/den ----
__global__ void norm_kernel(const float* __restrict__ F, __hip_bfloat16* __restrict__ Xb,
                            float* __restrict__ pos, float* __restrict__ den) {
    int lane = threadIdx.x & 63;
    int wave = threadIdx.x >> 6;
    int row  = blockIdx.x * 4 + wave;           // 2048 blocks x 4 waves = 8192 rows
    const float2 v = *(const float2*)(F + (size_t)row * DIM + lane * 2);
    float ss = v.x * v.x + v.y * v.y;
    #pragma unroll
    for (int m = 1; m < 64; m <<= 1) ss += __shfl_xor(ss, m);
    float inv = rsqrtf(ss) * SCALE;
    __hip_bfloat162 o;
    o.x = __float2bfloat16(v.x * inv);
    o.y = __float2bfloat16(v.y * inv);
    *((__hip_bfloat162*)(Xb + (size_t)row * DIM) + lane) = o;
    if (lane == 0) { pos[row] = 0.f; den[row] = 0.f; }
}

// ---- Kernel 2: fused gram + exp + row sums, barrier-free ----
// Block (rb, cg): rows [rb*128,+128) x col tiles ct = cg*2, cg*2+1.
// 4 waves 2x2 (wm,wn), each wave 64x64 per tile via 4x4 MFMA 16x16x32 bf16.
// A fragments register-resident (loaded once per block). B fragments loaded
// per tile straight from global/L2 (Xb = 2 MB, L2-resident; no LDS, no
// __syncthreads). MFMA accumulation is per-(mi,ni) 4-deep chains so the exp2
// epilogue (trans pipe) interleaves with MFMA issue of the other chains.
__global__ __launch_bounds__(256, 4) void gram_kernel(
        const __hip_bfloat16* __restrict__ Xb,
        float* __restrict__ pos, float* __restrict__ den) {
    const int tid  = threadIdx.x;
    const int rb   = blockIdx.x;      // 0..63
    const int cg   = blockIdx.y;      // 0..31
    const int lane = tid & 63;
    const int wave = tid >> 6;
    const int wm   = wave >> 1, wn = wave & 1;
    const int quad = lane >> 4;       // 0..3
    const int l15  = lane & 15;       // 0..15

    // A fragments: rows rb*128+wm*64+mi*16+l15, elems ko*32+quad*8 (one-time).
    short8 af[4][4];
    {
        const __hip_bfloat16* Ab = Xb + ((size_t)(rb * TILE + wm * 64 + l15)) * DIM + quad * 8;
        #pragma unroll
        for (int mi = 0; mi < 4; ++mi)
            #pragma unroll
            for (int ko = 0; ko < 4; ++ko)
                af[mi][ko] = *(const short8*)(Ab + mi * 16 * DIM + ko * 32);
    }

    float dp[4][4];   // row-sum accumulators
    #pragma unroll
    for (int a = 0; a < 4; ++a)
        #pragma unroll
        for (int b = 0; b < 4; ++b) dp[a][b] = 0.f;

    #pragma unroll 1
    for (int t = 0; t < CPG; ++t) {
        const int ct = cg * CPG + t;
        // B fragments: rows ct*128+wn*64+ni*16+l15, elems ko*32+quad*8.
        // Per wave-instruction: 16 rows x 64B quad-contiguous = 16 full lines.
        const __hip_bfloat16* Bb = Xb + ((size_t)(ct * TILE + wn * 64 + l15)) * DIM + quad * 8;
        short8 bf[4][4];
        #pragma unroll
        for (int ni = 0; ni < 4; ++ni)
            #pragma unroll
            for (int ko = 0; ko < 4; ++ko)
                bf[ni][ko] = *(const short8*)(Bb + ni * 16 * DIM + ko * 32);

        const bool pos_tile = (ct == rb) && (wm == wn);
        #pragma unroll
        for (int mi = 0; mi < 4; ++mi) {
            float dadd[4] = {0.f, 0.f, 0.f, 0.f};
            #pragma unroll
            for (int ni = 0; ni < 4; ++ni) {
                floatx4 acc = (floatx4)0.0f;
                #pragma unroll
                for (int ko = 0; ko < 4; ++ko)
                    acc = __builtin_amdgcn_mfma_f32_16x16x32_bf16(
                        af[mi][ko], bf[ni][ko], acc, 0, 0, 0);
                #pragma unroll
                for (int rg = 0; rg < 4; ++rg) {
                    float ex = EXP2F(acc[rg]);
                    // diagonal: replace bf16-noisy exp(10*||x||^2) with exact exp(10)
                    if (pos_tile && ni == mi && l15 == quad * 4 + rg)
                        ex = EXPTEN;
                    dadd[rg] += ex;
                }
            }
            #pragma unroll
            for (int rg = 0; rg < 4; ++rg) {
                if (pos_tile) {
                    float p = dadd[rg];
                    #pragma unroll
                    for (int m = 1; m < 16; m <<= 1) p += __shfl_xor(p, m);
                    if (l15 == 0)
                        atomicAdd(&pos[rb * TILE + wm * 64 + mi * 16 + quad * 4 + rg], p);
                }
                dp[mi][rg] += dadd[rg];
            }
        }
    }

    // den: reduce across the 16 lanes of each quad group, one atomic per row.
    #pragma unroll
    for (int mi = 0; mi < 4; ++mi)
        #pragma unroll
        for (int rg = 0; rg < 4; ++rg) {
            float d = dp[mi][rg];
            #pragma unroll
            for (int m = 1; m < 16; m <<= 1) d += __shfl_xor(d, m);
            if (l15 == 0)
                atomicAdd(&den[rb * TILE + wm * 64 + mi * 16 + quad * 4 + rg], d);
        }
}

// ---- Kernel 3: loss = mean(log(den/pos)) ----
__global__ void loss_kernel(const float* __restrict__ pos, const float* __restrict__ den,
                            float* __restrict__ out) {
    __shared__ float red[4];
    float acc = 0.f;
    for (int i = threadIdx.x; i < N_ROWS / 4; i += 256) {
        float4 d = ((const float4*)den)[i];
        float4 p = ((const float4*)pos)[i];
        acc += __logf(d.x / p.x) + __logf(d.y / p.y) +
               __logf(d.z / p.z) + __logf(d.w / p.w);
    }
    #pragma unroll
    for (int m = 1; m < 64; m <<= 1) acc += __shfl_xor(acc, m);
    int lane = threadIdx.x & 63, w = threadIdx.x >> 6;
    if (lane == 0) red[w] = acc;
    __syncthreads();
    if (threadIdx.x == 0)
        out[0] = (red[0] + red[1] + red[2] + red[3]) * (1.0f / (float)N_ROWS);
}

extern "C" void kernel_launch(void* const* d_in, const int* in_sizes, int n_in,
                              void* d_out, int out_size, void* d_ws, size_t ws_size,
                              hipStream_t stream) {
    const float* feature = (const float*)d_in[0];
    // ws layout: pos[8192] f32 | den[8192] f32 | Xb[8192*128] bf16
    float* pos = (float*)d_ws;
    float* den = pos + N_ROWS;
    __hip_bfloat16* Xb = (__hip_bfloat16*)(den + N_ROWS);

    norm_kernel<<<N_ROWS / 4, 256, 0, stream>>>(feature, Xb, pos, den);
    gram_kernel<<<dim3(64, N_ROWS / TILE / CPG), 256, 0, stream>>>(Xb, pos, den);
    loss_kernel<<<1, 256, 0, stream>>>(pos, den, (float*)d_out);
}

// Round 4
// 121.589 us; speedup vs baseline: 1.2475x; 1.2475x over previous
//
#include <hip/hip_runtime.h>
#include <hip/hip_bf16.h>

// feature [B=128, E=64, D=128] fp32 -> N = 8192 rows of dim 128.
// loss = mean_r( log(den_r) - log(pos_r) ),
//   den_r = sum_c exp(10*<f_r,f_c>), pos_r = sum over c in r's 64-row block.
//
// v5: v4's __launch_bounds__(256,4) forced VGPR 92->64, spilling the A/B
// fragment arrays to scratch (WRITE_SIZE 137 MB = spill traffic, gram 100us
// HBM-bound). Revert to (256,2): VGPR ~92, zero spill, HW still grants
// 4 waves/SIMD. Keep CPG=2 (2048 blocks) so occupancy is no longer
// grid-limited: ~4 resident blocks/CU = 16 waves/CU vs v3's 2 blocks.
#define N_ROWS 8192
#define DIM    128
#define TILE   128
#define CPG    2     // col tiles per block
#define EXPTEN 22026.465794806718f  // exp(10.0)
// Xb = normalize(f) * SCALE, SCALE^2 = 10*log2(e); then exp2(dot) = exp(10*<f,f>)
#define SCALE  3.7982826f

typedef __attribute__((ext_vector_type(8))) short short8;   // 8 bf16 = 4 VGPRs
typedef __attribute__((ext_vector_type(4))) float floatx4;  // MFMA C/D

#define EXP2F(x) __builtin_amdgcn_exp2f(x)

// ---- Kernel 1: L2-normalize rows, scale, cast to bf16; zero pos/den ----
__global__ void norm_kernel(const float* __restrict__ F, __hip_bfloat16* __restrict__ Xb,
                            float* __restrict__ pos, float* __restrict__ den) {
    int lane = threadIdx.x & 63;
    int wave = threadIdx.x >> 6;
    int row  = blockIdx.x * 4 + wave;           // 2048 blocks x 4 waves = 8192 rows
    const float2 v = *(const float2*)(F + (size_t)row * DIM + lane * 2);
    float ss = v.x * v.x + v.y * v.y;
    #pragma unroll
    for (int m = 1; m < 64; m <<= 1) ss += __shfl_xor(ss, m);
    float inv = rsqrtf(ss) * SCALE;
    __hip_bfloat162 o;
    o.x = __float2bfloat16(v.x * inv);
    o.y = __float2bfloat16(v.y * inv);
    *((__hip_bfloat162*)(Xb + (size_t)row * DIM) + lane) = o;
    if (lane == 0) { pos[row] = 0.f; den[row] = 0.f; }
}

// ---- Kernel 2: fused gram + exp + row sums, barrier-free ----
// Block (rb, cg): rows [rb*128,+128) x col tiles ct = cg*2, cg*2+1.
// 4 waves 2x2 (wm,wn), each wave 64x64 per tile via 4x4 MFMA 16x16x32 bf16.
// A fragments register-resident (loaded once per block). B fragments loaded
// per tile straight from global/L2 (Xb = 2 MB, L2-resident; no LDS, no
// __syncthreads). MFMA accumulation is per-(mi,ni) 4-deep chains so the exp2
// epilogue (trans pipe) interleaves with MFMA issue of the other chains.
__global__ __launch_bounds__(256, 2) void gram_kernel(
        const __hip_bfloat16* __restrict__ Xb,
        float* __restrict__ pos, float* __restrict__ den) {
    const int tid  = threadIdx.x;
    const int rb   = blockIdx.x;      // 0..63
    const int cg   = blockIdx.y;      // 0..31
    const int lane = tid & 63;
    const int wave = tid >> 6;
    const int wm   = wave >> 1, wn = wave & 1;
    const int quad = lane >> 4;       // 0..3
    const int l15  = lane & 15;       // 0..15

    // A fragments: rows rb*128+wm*64+mi*16+l15, elems ko*32+quad*8 (one-time).
    short8 af[4][4];
    {
        const __hip_bfloat16* Ab = Xb + ((size_t)(rb * TILE + wm * 64 + l15)) * DIM + quad * 8;
        #pragma unroll
        for (int mi = 0; mi < 4; ++mi)
            #pragma unroll
            for (int ko = 0; ko < 4; ++ko)
                af[mi][ko] = *(const short8*)(Ab + mi * 16 * DIM + ko * 32);
    }

    float dp[4][4];   // row-sum accumulators
    #pragma unroll
    for (int a = 0; a < 4; ++a)
        #pragma unroll
        for (int b = 0; b < 4; ++b) dp[a][b] = 0.f;

    #pragma unroll 1
    for (int t = 0; t < CPG; ++t) {
        const int ct = cg * CPG + t;
        // B fragments: rows ct*128+wn*64+ni*16+l15, elems ko*32+quad*8.
        // Per wave-instruction: 16 rows x 64B quad-contiguous = 16 full lines.
        const __hip_bfloat16* Bb = Xb + ((size_t)(ct * TILE + wn * 64 + l15)) * DIM + quad * 8;
        short8 bf[4][4];
        #pragma unroll
        for (int ni = 0; ni < 4; ++ni)
            #pragma unroll
            for (int ko = 0; ko < 4; ++ko)
                bf[ni][ko] = *(const short8*)(Bb + ni * 16 * DIM + ko * 32);

        const bool pos_tile = (ct == rb) && (wm == wn);
        #pragma unroll
        for (int mi = 0; mi < 4; ++mi) {
            float dadd[4] = {0.f, 0.f, 0.f, 0.f};
            #pragma unroll
            for (int ni = 0; ni < 4; ++ni) {
                floatx4 acc = (floatx4)0.0f;
                #pragma unroll
                for (int ko = 0; ko < 4; ++ko)
                    acc = __builtin_amdgcn_mfma_f32_16x16x32_bf16(
                        af[mi][ko], bf[ni][ko], acc, 0, 0, 0);
                #pragma unroll
                for (int rg = 0; rg < 4; ++rg) {
                    float ex = EXP2F(acc[rg]);
                    // diagonal: replace bf16-noisy exp(10*||x||^2) with exact exp(10)
                    if (pos_tile && ni == mi && l15 == quad * 4 + rg)
                        ex = EXPTEN;
                    dadd[rg] += ex;
                }
            }
            #pragma unroll
            for (int rg = 0; rg < 4; ++rg) {
                if (pos_tile) {
                    float p = dadd[rg];
                    #pragma unroll
                    for (int m = 1; m < 16; m <<= 1) p += __shfl_xor(p, m);
                    if (l15 == 0)
                        atomicAdd(&pos[rb * TILE + wm * 64 + mi * 16 + quad * 4 + rg], p);
                }
                dp[mi][rg] += dadd[rg];
            }
        }
    }

    // den: reduce across the 16 lanes of each quad group, one atomic per row.
    #pragma unroll
    for (int mi = 0; mi < 4; ++mi)
        #pragma unroll
        for (int rg = 0; rg < 4; ++rg) {
            float d = dp[mi][rg];
            #pragma unroll
            for (int m = 1; m < 16; m <<= 1) d += __shfl_xor(d, m);
            if (l15 == 0)
                atomicAdd(&den[rb * TILE + wm * 64 + mi * 16 + quad * 4 + rg], d);
        }
}

// ---- Kernel 3: loss = mean(log(den/pos)) ----
__global__ void loss_kernel(const float* __restrict__ pos, const float* __restrict__ den,
                            float* __restrict__ out) {
    __shared__ float red[4];
    float acc = 0.f;
    for (int i = threadIdx.x; i < N_ROWS / 4; i += 256) {
        float4 d = ((const float4*)den)[i];
        float4 p = ((const float4*)pos)[i];
        acc += __logf(d.x / p.x) + __logf(d.y / p.y) +
               __logf(d.z / p.z) + __logf(d.w / p.w);
    }
    #pragma unroll
    for (int m = 1; m < 64; m <<= 1) acc += __shfl_xor(acc, m);
    int lane = threadIdx.x & 63, w = threadIdx.x >> 6;
    if (lane == 0) red[w] = acc;
    __syncthreads();
    if (threadIdx.x == 0)
        out[0] = (red[0] + red[1] + red[2] + red[3]) * (1.0f / (float)N_ROWS);
}

extern "C" void kernel_launch(void* const* d_in, const int* in_sizes, int n_in,
                              void* d_out, int out_size, void* d_ws, size_t ws_size,
                              hipStream_t stream) {
    const float* feature = (const float*)d_in[0];
    // ws layout: pos[8192] f32 | den[8192] f32 | Xb[8192*128] bf16
    float* pos = (float*)d_ws;
    float* den = pos + N_ROWS;
    __hip_bfloat16* Xb = (__hip_bfloat16*)(den + N_ROWS);

    norm_kernel<<<N_ROWS / 4, 256, 0, stream>>>(feature, Xb, pos, den);
    gram_kernel<<<dim3(64, N_ROWS / TILE / CPG), 256, 0, stream>>>(Xb, pos, den);
    loss_kernel<<<1, 256, 0, stream>>>(pos, den, (float*)d_out);
}

// Round 5
// 98.973 us; speedup vs baseline: 1.5325x; 1.2285x over previous
//
#include <hip/hip_runtime.h>
#include <hip/hip_bf16.h>

// feature [B=128, E=64, D=128] fp32 -> N = 8192 rows of dim 128.
// loss = mean_r( log(den_r) - log(pos_r) ),
//   den_r = sum_c exp(10*<f_r,f_c>), pos_r = sum over c in r's 64-row block.
//
// v6: occupancy is register-capped (~2 waves/SIMD; 92 arch + ~64 acc VGPRs,
// unified file) -> TLP cannot hide the ~900cyc B-load latency (v3/v5 showed
// ~15K cyc/tile = 16 loads serialized). Fix with ILP: quarter-tile register
// pipeline. B lives in 4 quarter-buffers bq[ni][0..3]; per quarter we compute
// the 4 (mi,ni) MFMA chains then immediately refill that quarter with the
// NEXT tile's data, keeping ~12 loads in flight under ~850 cyc of compute.
// No LDS, no barriers -> compiler emits counted vmcnt waits per buffer.
// CPG=8 -> 512 blocks = exactly 2/CU, A-fragments amortized over 8 tiles.
#define N_ROWS 8192
#define DIM    128
#define TILE   128
#define CPG    8     // col tiles per block
#define EXPTEN 22026.465794806718f  // exp(10.0)
// Xb = normalize(f) * SCALE, SCALE^2 = 10*log2(e); then exp2(dot) = exp(10*<f,f>)
#define SCALE  3.7982826f

typedef __attribute__((ext_vector_type(8))) short short8;   // 8 bf16 = 4 VGPRs
typedef __attribute__((ext_vector_type(4))) float floatx4;  // MFMA C/D

#define EXP2F(x) __builtin_amdgcn_exp2f(x)

// ---- Kernel 1: L2-normalize rows, scale, cast to bf16; zero pos/den ----
__global__ void norm_kernel(const float* __restrict__ F, __hip_bfloat16* __restrict__ Xb,
                            float* __restrict__ pos, float* __restrict__ den) {
    int lane = threadIdx.x & 63;
    int wave = threadIdx.x >> 6;
    int row  = blockIdx.x * 4 + wave;           // 2048 blocks x 4 waves = 8192 rows
    const float2 v = *(const float2*)(F + (size_t)row * DIM + lane * 2);
    float ss = v.x * v.x + v.y * v.y;
    #pragma unroll
    for (int m = 1; m < 64; m <<= 1) ss += __shfl_xor(ss, m);
    float inv = rsqrtf(ss) * SCALE;
    __hip_bfloat162 o;
    o.x = __float2bfloat16(v.x * inv);
    o.y = __float2bfloat16(v.y * inv);
    *((__hip_bfloat162*)(Xb + (size_t)row * DIM) + lane) = o;
    if (lane == 0) { pos[row] = 0.f; den[row] = 0.f; }
}

// ---- Kernel 2: fused gram + exp + row sums, barrier-free, reg-pipelined ----
__global__ __launch_bounds__(256, 2) void gram_kernel(
        const __hip_bfloat16* __restrict__ Xb,
        float* __restrict__ pos, float* __restrict__ den) {
    const int tid  = threadIdx.x;
    const int rb   = blockIdx.x;      // 0..63
    const int cg   = blockIdx.y;      // 0..7
    const int lane = tid & 63;
    const int wave = tid >> 6;
    const int wm   = wave >> 1, wn = wave & 1;
    const int quad = lane >> 4;       // 0..3
    const int l15  = lane & 15;       // 0..15

    // A fragments: rows rb*128+wm*64+mi*16+l15, elems ko*32+quad*8 (one-time).
    short8 af[4][4];
    {
        const __hip_bfloat16* Ab = Xb + ((size_t)(rb * TILE + wm * 64 + l15)) * DIM + quad * 8;
        #pragma unroll
        for (int mi = 0; mi < 4; ++mi)
            #pragma unroll
            for (int ko = 0; ko < 4; ++ko)
                af[mi][ko] = *(const short8*)(Ab + mi * 16 * DIM + ko * 32);
    }

    float dp[4][4];   // row-sum accumulators (whole block's col range)
    #pragma unroll
    for (int a = 0; a < 4; ++a)
        #pragma unroll
        for (int b = 0; b < 4; ++b) dp[a][b] = 0.f;

    // B base for this wave: rows ct*128 + wn*64 + ni*16 + l15, elems ko*32+quad*8.
    const __hip_bfloat16* Bb =
        Xb + ((size_t)(cg * CPG * TILE + wn * 64 + l15)) * DIM + quad * 8;

    // Quarter buffers: bq[ni][ko], constant indices via full unroll (no scratch).
    short8 bq[4][4];
    #pragma unroll
    for (int ni = 0; ni < 4; ++ni)
        #pragma unroll
        for (int ko = 0; ko < 4; ++ko)
            bq[ni][ko] = *(const short8*)(Bb + ni * 16 * DIM + ko * 32);

    // One tile's work: compute per-quarter, optionally refilling that quarter
    // with the next tile's data right after its last consumer.
    auto do_tile = [&](int t, bool refill) {
        const int ct = cg * CPG + t;
        const bool pos_tile = (ct == rb) && (wm == wn);
        const __hip_bfloat16* Bn = Bb + (size_t)(t + 1) * TILE * DIM;

        float dadd[4][4];
        #pragma unroll
        for (int mi = 0; mi < 4; ++mi)
            #pragma unroll
            for (int rg = 0; rg < 4; ++rg) dadd[mi][rg] = 0.f;

        #pragma unroll
        for (int ni = 0; ni < 4; ++ni) {
            floatx4 acc[4];
            #pragma unroll
            for (int mi = 0; mi < 4; ++mi) acc[mi] = (floatx4)0.0f;
            #pragma unroll
            for (int ko = 0; ko < 4; ++ko)
                #pragma unroll
                for (int mi = 0; mi < 4; ++mi)
                    acc[mi] = __builtin_amdgcn_mfma_f32_16x16x32_bf16(
                        af[mi][ko], bq[ni][ko], acc[mi], 0, 0, 0);
            // refill this quarter for tile t+1 (loads issue after last read of bq[ni])
            if (refill)
                #pragma unroll
                for (int ko = 0; ko < 4; ++ko)
                    bq[ni][ko] = *(const short8*)(Bn + ni * 16 * DIM + ko * 32);
            // epilogue of the 4 chains: exp2 (trans pipe) + accumulate
            #pragma unroll
            for (int mi = 0; mi < 4; ++mi)
                #pragma unroll
                for (int rg = 0; rg < 4; ++rg) {
                    float ex = EXP2F(acc[mi][rg]);
                    // diagonal: replace bf16-noisy exp(10*||x||^2) with exact exp(10)
                    if (pos_tile && ni == mi && l15 == quad * 4 + rg)
                        ex = EXPTEN;
                    dadd[mi][rg] += ex;
                }
        }

        #pragma unroll
        for (int mi = 0; mi < 4; ++mi)
            #pragma unroll
            for (int rg = 0; rg < 4; ++rg) {
                if (pos_tile) {
                    float p = dadd[mi][rg];
                    #pragma unroll
                    for (int m = 1; m < 16; m <<= 1) p += __shfl_xor(p, m);
                    if (l15 == 0)
                        atomicAdd(&pos[rb * TILE + wm * 64 + mi * 16 + quad * 4 + rg], p);
                }
                dp[mi][rg] += dadd[mi][rg];
            }
    };

    #pragma unroll 1
    for (int t = 0; t < CPG - 1; ++t)
        do_tile(t, true);
    do_tile(CPG - 1, false);   // peeled tail: no refill, no OOB reads

    // den: reduce across the 16 lanes of each quad group, one atomic per row.
    #pragma unroll
    for (int mi = 0; mi < 4; ++mi)
        #pragma unroll
        for (int rg = 0; rg < 4; ++rg) {
            float d = dp[mi][rg];
            #pragma unroll
            for (int m = 1; m < 16; m <<= 1) d += __shfl_xor(d, m);
            if (l15 == 0)
                atomicAdd(&den[rb * TILE + wm * 64 + mi * 16 + quad * 4 + rg], d);
        }
}

// ---- Kernel 3: loss = mean(log(den/pos)) ----
__global__ void loss_kernel(const float* __restrict__ pos, const float* __restrict__ den,
                            float* __restrict__ out) {
    __shared__ float red[4];
    float acc = 0.f;
    for (int i = threadIdx.x; i < N_ROWS / 4; i += 256) {
        float4 d = ((const float4*)den)[i];
        float4 p = ((const float4*)pos)[i];
        acc += __logf(d.x / p.x) + __logf(d.y / p.y) +
               __logf(d.z / p.z) + __logf(d.w / p.w);
    }
    #pragma unroll
    for (int m = 1; m < 64; m <<= 1) acc += __shfl_xor(acc, m);
    int lane = threadIdx.x & 63, w = threadIdx.x >> 6;
    if (lane == 0) red[w] = acc;
    __syncthreads();
    if (threadIdx.x == 0)
        out[0] = (red[0] + red[1] + red[2] + red[3]) * (1.0f / (float)N_ROWS);
}

extern "C" void kernel_launch(void* const* d_in, const int* in_sizes, int n_in,
                              void* d_out, int out_size, void* d_ws, size_t ws_size,
                              hipStream_t stream) {
    const float* feature = (const float*)d_in[0];
    // ws layout: pos[8192] f32 | den[8192] f32 | Xb[8192*128] bf16
    float* pos = (float*)d_ws;
    float* den = pos + N_ROWS;
    __hip_bfloat16* Xb = (__hip_bfloat16*)(den + N_ROWS);

    norm_kernel<<<N_ROWS / 4, 256, 0, stream>>>(feature, Xb, pos, den);
    gram_kernel<<<dim3(64, N_ROWS / TILE / CPG), 256, 0, stream>>>(Xb, pos, den);
    loss_kernel<<<1, 256, 0, stream>>>(pos, den, (float*)d_out);
}